// Round 8
// baseline (12247.853 us; speedup 1.0000x reference)
//
#include <hip/hip_runtime.h>

#define FF 512
#define HH 1024
#define LL 128
#define BB 128
#define PP 1024

typedef short short8 __attribute__((ext_vector_type(8)));
typedef float floatx4 __attribute__((ext_vector_type(4)));
typedef unsigned short ushort_t;
typedef unsigned long long u64;

__device__ __forceinline__ float sigm(float x) {
    return 1.0f / (1.0f + __expf(-x));
}
// overflow-safe tanh: exp(-2|x|) underflows to 0 for large |x| -> +-1
__device__ __forceinline__ float tanh_fast(float x) {
    float ax = fabsf(x);
    float e = __expf(-2.0f * ax);
    float r = (1.0f - e) / (1.0f + e);
    return copysignf(r, x);
}

__device__ __forceinline__ unsigned short bf16_rtne(float x) {
    unsigned int u = __float_as_uint(x);
    return (unsigned short)((u + 0x7FFFu + ((u >> 16) & 1u)) >> 16);
}
__device__ __forceinline__ void split_bf16(float x, unsigned short& hi, unsigned short& lo) {
    hi = bf16_rtne(x);
    float hf = __uint_as_float(((unsigned int)hi) << 16);
    lo = bf16_rtne(x - hf);
}

// --- agent-scope h exchange: coherent across XCDs (verified R3/R4) ---
__device__ __forceinline__ int4 ld_h16(const ushort_t* p) {
    u64* q = (u64*)p;
    u64 a = __hip_atomic_load(q,     __ATOMIC_RELAXED, __HIP_MEMORY_SCOPE_AGENT);
    u64 b = __hip_atomic_load(q + 1, __ATOMIC_RELAXED, __HIP_MEMORY_SCOPE_AGENT);
    return make_int4((int)(unsigned)(a & 0xffffffffull), (int)(unsigned)(a >> 32),
                     (int)(unsigned)(b & 0xffffffffull), (int)(unsigned)(b >> 32));
}
__device__ __forceinline__ void st_h8(ushort_t* p, uint2 v) {
    u64 x = ((u64)v.y << 32) | (u64)v.x;
    __hip_atomic_store((u64*)p, x, __ATOMIC_RELAXED, __HIP_MEMORY_SCOPE_AGENT);
}
__device__ __forceinline__ float4 ld_f4_bypass(const float* p) {
    u64* q = (u64*)p;
    u64 a = __hip_atomic_load(q,     __ATOMIC_RELAXED, __HIP_MEMORY_SCOPE_AGENT);
    u64 b = __hip_atomic_load(q + 1, __ATOMIC_RELAXED, __HIP_MEMORY_SCOPE_AGENT);
    float4 r;
    ((u64*)&r)[0] = a;
    ((u64*)&r)[1] = b;
    return r;
}

// monotonic-counter grid barrier (VERIFIED R3/R4): tid0 arrives and spins;
// other waves park in the trailing __syncthreads. The leading __syncthreads
// drains every wave's vmcnt -> all h atomic-stores globally visible.
__device__ __forceinline__ void grid_barrier(unsigned* cnt, unsigned target, int tid) {
    __syncthreads();
    if (tid == 0) {
        __hip_atomic_fetch_add(cnt, 1u, __ATOMIC_RELAXED, __HIP_MEMORY_SCOPE_AGENT);
        while (__hip_atomic_load(cnt, __ATOMIC_RELAXED, __HIP_MEMORY_SCOPE_AGENT) < target) {
            __builtin_amdgcn_s_sleep(2);
        }
    }
    __syncthreads();
}

__global__ void fillz(float* p, int n) {
    int i = blockIdx.x * blockDim.x + threadIdx.x;
    if (i < n) p[i] = 0.0f;
}

// fp32 [n] -> bf16 hi/lo [n]
__global__ void split_w(const float* __restrict__ W, ushort_t* __restrict__ hi,
                        ushort_t* __restrict__ lo, int n) {
    int i = blockIdx.x * blockDim.x + threadIdx.x;
    if (i < n) {
        unsigned short h, l;
        split_bf16(W[i], h, l);
        hi[i] = h; lo[i] = l;
    }
}

// ---------------------------------------------------------------------------
// Persistent cooperative encoder, v5 (16 waves/CU via 1024-thread blocks):
// R5/R6 failed with identical deterministic absmax regardless of barrier
// state -> prime suspect: 512-block cooperative launch silently rejected
// (co-residency check) so the encoder never ran. This version keeps EVERY
// verified element of R4 (grid 256, single-counter barrier, agent-atomic h
// exchange, epilogue mapping, accumulation order) and doubles wave
// parallelism inside the block instead: 1024 threads = 16 waves,
// wave = (gate g, f-half fh, K-half kh). Each wave: 32x32 quadrant,
// acc[2][2], 24 MFMA/chunk (half of v4's 48 -> per-wave critical path
// halved). A: 8 quadrant regions x 8 KB = 64 KB LDS. B fragments are
// fh-independent (same addresses as v4; fh-pair waves duplicate loads, L1
// hits). Gx reduce: kh=1 writes, kh=0 adds -> same 2-way K-split order as
// v4 -> bit-identical results.
// ---------------------------------------------------------------------------
__global__ __launch_bounds__(1024, 4) void lstm_encoder_persistent(
    ushort_t* __restrict__ hhiA, ushort_t* __restrict__ hloA,   // buf0 (zeroed)
    ushort_t* __restrict__ hhiB, ushort_t* __restrict__ hloB,   // buf1
    float* __restrict__ h_fin,   // fp32 final h   (h_a)
    float* __restrict__ c_fin,   // fp32 final c   (c_st)
    const ushort_t* __restrict__ Whi1, const ushort_t* __restrict__ Wlo1,
    const ushort_t* __restrict__ Whi2, const ushort_t* __restrict__ Wlo2,
    const float* __restrict__ emb1, const float* __restrict__ emb2,
    const int* __restrict__ tok1, const int* __restrict__ len1,
    const int* __restrict__ tok2, const int* __restrict__ len2,
    unsigned* __restrict__ barCnt)
{
    // A regions: ((fh*2+kh)*2 + parity)*8192; within region hi @+0, lo @+4096.
    __shared__ __align__(16) char smem[65536];
    float* Gx = (float*)smem;            // epilogue reuse: [4][64][36] fp32

    const int tid = threadIdx.x;
    const int w = tid >> 6;              // wave 0..15
    const int g = w & 3;                 // gate
    const int fh = (w >> 2) & 1;         // f-half 0/1
    const int kh = w >> 3;               // K-half 0/1
    const int l = tid & 63;
    const int q = l >> 4;                // k-quad 0..3
    const int fr = l & 15;               // fragment row/col

    // XCD-aware decode (VERIFIED v4): xcd = id&7
    const int id = blockIdx.x;
    const int by = (id & 7) + 8 * ((id >> 3) & 3);
    const int bx = id >> 5;
    const int fbase = bx * 64;
    const int n0 = by * 32;

    // --- A staging map: quadrant qgrp = tid>>8; 1x16B hi + 1x16B lo/thread
    const int qgrp = tid >> 8;           // 0..3
    const int sfh = qgrp & 1;            // staged f-half
    const int skh = qgrp >> 1;           // staged K-half
    const int u = tid & 255;
    const int ar = u >> 3;               // row-in-quadrant 0..31
    const int s0 = u & 7;                // slot 0..7
    const size_t a_goff = (size_t)(fbase + sfh * 32 + ar) * HH + skh * 512 + s0 * 8;
    const int lds = ar * 8 + ((s0 + ar) & 7);
    const int qidx = sfh * 2 + skh;      // staging region group

    // --- B fragment offsets (fh-independent, same as v4) ---
    const size_t brow0 = ((size_t)(g * HH) + n0 + fr) * HH + q * 8 + kh * 512;
    const size_t brow1 = ((size_t)(g * HH) + n0 + 16 + fr) * HH + q * 8 + kh * 512;

    // --- epilogue map (threads 0..511, VERIFIED v4) + persistent cell state
    const int rr = (tid & 511) >> 3;     // row 0..63
    const int c0 = (tid & 7) * 4;
    const int f = fbase + rr;
    const int gc = n0 + c0;
    const size_t gidx = (size_t)f * HH + gc;
    float4 creg = make_float4(0.f, 0.f, 0.f, 0.f);
    float4 hreg = make_float4(0.f, 0.f, 0.f, 0.f);

    // B double buffer; prefetch chunk0 of t=0
    short8 Bh[2][2][2], Bl[2][2][2];
    #pragma unroll
    for (int kk = 0; kk < 2; ++kk) {
        Bh[0][0][kk] = *(const short8*)(Whi1 + brow0 + kk * 32);
        Bh[0][1][kk] = *(const short8*)(Whi1 + brow1 + kk * 32);
        Bl[0][0][kk] = *(const short8*)(Wlo1 + brow0 + kk * 32);
        Bl[0][1][kk] = *(const short8*)(Wlo1 + brow1 + kk * 32);
    }

    for (int t = 0; t < 256; ++t) {
        const int tt = t & 127;
        const bool ph2 = t >= 128;
        const ushort_t* Wh = ph2 ? Whi2 : Whi1;
        const ushort_t* Wl = ph2 ? Wlo2 : Wlo1;
        const ushort_t* WhN = (t >= 127) ? Whi2 : Whi1;  // base for t+1
        const ushort_t* WlN = (t >= 127) ? Wlo2 : Wlo1;
        const float* emb = ph2 ? emb2 : emb1;
        const int* tok = ph2 ? tok2 : tok1;
        const int* len = ph2 ? len2 : len1;
        const ushort_t* rhh = (t & 1) ? hhiB : hhiA;
        const ushort_t* rhl = (t & 1) ? hloB : hloA;
        ushort_t* whh = (t & 1) ? hhiA : hhiB;
        ushort_t* whl = (t & 1) ? hloA : hloB;

        // A chunk 0 -> LDS region (qidx, 0)
        {
            int4 h0 = ld_h16(rhh + a_goff);
            int4 l0v = ld_h16(rhl + a_goff);
            char* R0 = smem + qidx * 16384;
            ((int4*)R0)[lds] = h0;
            ((int4*)(R0 + 4096))[lds] = l0v;
        }
        __syncthreads();

        floatx4 acc[2][2];
        #pragma unroll
        for (int m = 0; m < 2; ++m)
            #pragma unroll
            for (int n = 0; n < 2; ++n) acc[m][n] = (floatx4)(0.0f);

        int4 pa_h, pa_l;
        #pragma unroll 2
        for (int i = 0; i < 8; ++i) {
            const int cur = i & 1, nxt = cur ^ 1;
            const char* AsH = smem + ((fh * 2 + kh) * 2 + cur) * 8192;
            const char* AsL = AsH + 4096;

            // A prefetch for local chunk i+1 (this thread's quadrant)
            if (i < 7) {
                const int k0 = (i + 1) * 64;
                pa_h = ld_h16(rhh + a_goff + k0);
                pa_l = ld_h16(rhl + a_goff + k0);
            }
            // B prefetch: chunks 1..7, or chunk0 of NEXT step at i==7
            {
                const ushort_t* Bsh = (i < 7) ? Wh : WhN;
                const ushort_t* Bsl = (i < 7) ? Wl : WlN;
                const int k0 = (i < 7) ? (i + 1) * 64 : 0;
                #pragma unroll
                for (int kk = 0; kk < 2; ++kk) {
                    Bh[nxt][0][kk] = *(const short8*)(Bsh + brow0 + k0 + kk * 32);
                    Bh[nxt][1][kk] = *(const short8*)(Bsh + brow1 + k0 + kk * 32);
                    Bl[nxt][0][kk] = *(const short8*)(Bsl + brow0 + k0 + kk * 32);
                    Bl[nxt][1][kk] = *(const short8*)(Bsl + brow1 + k0 + kk * 32);
                }
            }

            // compute local chunk i from region (fh, kh, cur)
            #pragma unroll
            for (int m = 0; m < 2; ++m) {
                const int r = m * 16 + fr;   // row-in-quadrant 0..31
                short8 ah0 = *(const short8*)(AsH + (r * 8 + ((q + r) & 7)) * 16);
                short8 ah1 = *(const short8*)(AsH + (r * 8 + ((4 + q + r) & 7)) * 16);
                short8 al0 = *(const short8*)(AsL + (r * 8 + ((q + r) & 7)) * 16);
                short8 al1 = *(const short8*)(AsL + (r * 8 + ((4 + q + r) & 7)) * 16);
                #pragma unroll
                for (int n = 0; n < 2; ++n) {
                    acc[m][n] = __builtin_amdgcn_mfma_f32_16x16x32_bf16(ah0, Bh[cur][n][0], acc[m][n], 0, 0, 0);
                    acc[m][n] = __builtin_amdgcn_mfma_f32_16x16x32_bf16(al0, Bh[cur][n][0], acc[m][n], 0, 0, 0);
                    acc[m][n] = __builtin_amdgcn_mfma_f32_16x16x32_bf16(ah0, Bl[cur][n][0], acc[m][n], 0, 0, 0);
                    acc[m][n] = __builtin_amdgcn_mfma_f32_16x16x32_bf16(ah1, Bh[cur][n][1], acc[m][n], 0, 0, 0);
                    acc[m][n] = __builtin_amdgcn_mfma_f32_16x16x32_bf16(al1, Bh[cur][n][1], acc[m][n], 0, 0, 0);
                    acc[m][n] = __builtin_amdgcn_mfma_f32_16x16x32_bf16(ah1, Bl[cur][n][1], acc[m][n], 0, 0, 0);
                }
            }

            if (i < 7) {
                char* DH = smem + (qidx * 2 + nxt) * 8192;
                ((int4*)DH)[lds] = pa_h;
                ((int4*)(DH + 4096))[lds] = pa_l;
            }
            __syncthreads();
        }

        // --- K-half reduce (C/D layout: col=fr, row=q*4+reg); rows fh*32+ --
        if (kh == 1) {
            #pragma unroll
            for (int m = 0; m < 2; ++m)
                #pragma unroll
                for (int n = 0; n < 2; ++n)
                    #pragma unroll
                    for (int r = 0; r < 4; ++r)
                        Gx[(g * 64 + fh * 32 + m * 16 + q * 4 + r) * 36 + n * 16 + fr] = acc[m][n][r];
        }
        __syncthreads();
        if (kh == 0) {
            #pragma unroll
            for (int m = 0; m < 2; ++m)
                #pragma unroll
                for (int n = 0; n < 2; ++n)
                    #pragma unroll
                    for (int r = 0; r < 4; ++r) {
                        const int idx = (g * 64 + fh * 32 + m * 16 + q * 4 + r) * 36 + n * 16 + fr;
                        Gx[idx] += acc[m][n][r];
                    }
        }
        __syncthreads();

        // --- fused cell update (threads 0..511, VERIFIED v4 mapping) ---
        if (tid < 512) {
            const float* ib = emb + (size_t)tok[f * LL + tt] * 4096;
            const bool upd = tt < len[f];

            float4 gv[4];
            #pragma unroll
            for (int gg = 0; gg < 4; ++gg) {
                gv[gg] = *(const float4*)&Gx[(gg * 64 + rr) * 36 + c0];
                const float4 ibv = ld_f4_bypass(ib + gg * 1024 + gc);
                gv[gg].x += ibv.x; gv[gg].y += ibv.y; gv[gg].z += ibv.z; gv[gg].w += ibv.w;
            }

            unsigned short hb[4], lb[4];
            {
                const float* gi = (const float*)&gv[0];
                const float* gf = (const float*)&gv[1];
                const float* gn = (const float*)&gv[2];
                const float* go = (const float*)&gv[3];
                float* cr = (float*)&creg;
                float* hr = (float*)&hreg;
                #pragma unroll
                for (int j = 0; j < 4; ++j) {
                    float cn = sigm(gf[j]) * cr[j] + sigm(gi[j]) * tanh_fast(gn[j]);
                    float hn = sigm(go[j]) * tanh_fast(cn);
                    if (upd) { cr[j] = cn; hr[j] = hn; }
                    split_bf16(hr[j], hb[j], lb[j]);
                }
            }
            uint2 hp, lp;
            hp.x = (unsigned)hb[0] | ((unsigned)hb[1] << 16);
            hp.y = (unsigned)hb[2] | ((unsigned)hb[3] << 16);
            lp.x = (unsigned)lb[0] | ((unsigned)lb[1] << 16);
            lp.y = (unsigned)lb[2] | ((unsigned)lb[3] << 16);
            st_h8(whh + gidx, hp);
            st_h8(whl + gidx, lp);
            if (t == 255) {
                *(float4*)(h_fin + gidx) = hreg;
                *(float4*)(c_fin + gidx) = creg;
            }
        }

        grid_barrier(barCnt, 256u * (unsigned)(t + 1), tid);
    }
}

// ---------------------------------------------------------------------------
// bf16-split MFMA LSTM step (v4, 8-wave K-split) — used by the 16 decoder
// steps (initE = u_p, tokens/lengths = null). Unchanged.
// ---------------------------------------------------------------------------
__global__ __launch_bounds__(512, 2) void lstm_step_mfma(
    const float* __restrict__ h_in,
    const ushort_t* __restrict__ hhi,
    const ushort_t* __restrict__ hlo,
    float* __restrict__ h_out,
    ushort_t* __restrict__ hhi_o,
    ushort_t* __restrict__ hlo_o,
    float* __restrict__ c_st,
    const ushort_t* __restrict__ Whi,
    const ushort_t* __restrict__ Wlo,
    const float* __restrict__ initE,
    const int* __restrict__ tokens,
    const int* __restrict__ lengths,
    int t)
{
    __shared__ __align__(16) char smem[65536];
    float* Gx = (float*)smem;

    const int tid = threadIdx.x;
    const int w = tid >> 6;
    const int g = w & 3;
    const int kh = w >> 2;
    const int l = tid & 63;
    const int q = l >> 4;
    const int fr = l & 15;

    const int id = blockIdx.x;
    const int by = (id & 7) + 8 * ((id >> 3) & 3);
    const int bx = id >> 5;
    const int fbase = bx * 64;
    const int n0 = by * 32;

    const int sgrp = tid >> 8;
    const int u = tid & 255;
    const int ar = u >> 2;
    const int s0 = u & 3;
    const size_t a_goff = (size_t)(fbase + ar) * HH + s0 * 8 + sgrp * 512;
    const int sw0 = (s0 + ar) & 7;
    const int sw1 = ((s0 + 4) + ar) & 7;
    const int lds0 = ar * 8 + sw0;
    const int lds1 = ar * 8 + sw1;

    const size_t brow0 = ((size_t)(g * HH) + n0 + 0 * 16 + fr) * HH + q * 8 + kh * 512;
    const size_t brow1 = ((size_t)(g * HH) + n0 + 16 + fr) * HH + q * 8 + kh * 512;

    floatx4 acc[4][2];
    #pragma unroll
    for (int m = 0; m < 4; ++m)
        #pragma unroll
        for (int n = 0; n < 2; ++n) acc[m][n] = (floatx4)(0.0f);

    int4 pa_h0 = *(const int4*)(hhi + a_goff);
    int4 pa_h1 = *(const int4*)(hhi + a_goff + 32);
    int4 pa_l0 = *(const int4*)(hlo + a_goff);
    int4 pa_l1 = *(const int4*)(hlo + a_goff + 32);

    short8 Bh[2][2][2], Bl[2][2][2];
    #pragma unroll
    for (int kk = 0; kk < 2; ++kk) {
        Bh[0][0][kk] = *(const short8*)(Whi + brow0 + kk * 32);
        Bh[0][1][kk] = *(const short8*)(Whi + brow1 + kk * 32);
        Bl[0][0][kk] = *(const short8*)(Wlo + brow0 + kk * 32);
        Bl[0][1][kk] = *(const short8*)(Wlo + brow1 + kk * 32);
    }

    {
        char* R0 = smem + sgrp * 32768;
        ((int4*)R0)[lds0] = pa_h0;
        ((int4*)R0)[lds1] = pa_h1;
        ((int4*)(R0 + 8192))[lds0] = pa_l0;
        ((int4*)(R0 + 8192))[lds1] = pa_l1;
    }
    __syncthreads();

    #pragma unroll 2
    for (int i = 0; i < 8; ++i) {
        const int cur = i & 1, nxt = cur ^ 1;
        const char* AsH = smem + (kh * 2 + cur) * 16384;
        const char* AsL = AsH + 8192;

        if (i < 7) {
            const int k0 = (i + 1) * 64;
            pa_h0 = *(const int4*)(hhi + a_goff + k0);
            pa_h1 = *(const int4*)(hhi + a_goff + k0 + 32);
            pa_l0 = *(const int4*)(hlo + a_goff + k0);
            pa_l1 = *(const int4*)(hlo + a_goff + k0 + 32);
            #pragma unroll
            for (int kk = 0; kk < 2; ++kk) {
                Bh[nxt][0][kk] = *(const short8*)(Whi + brow0 + k0 + kk * 32);
                Bh[nxt][1][kk] = *(const short8*)(Whi + brow1 + k0 + kk * 32);
                Bl[nxt][0][kk] = *(const short8*)(Wlo + brow0 + k0 + kk * 32);
                Bl[nxt][1][kk] = *(const short8*)(Wlo + brow1 + k0 + kk * 32);
            }
        }

        #pragma unroll
        for (int m = 0; m < 4; ++m) {
            const int r = m * 16 + fr;
            short8 ah0 = *(const short8*)(AsH + (r * 8 + ((0 * 4 + q + r) & 7)) * 16);
            short8 ah1 = *(const short8*)(AsH + (r * 8 + ((1 * 4 + q + r) & 7)) * 16);
            short8 al0 = *(const short8*)(AsL + (r * 8 + ((0 * 4 + q + r) & 7)) * 16);
            short8 al1 = *(const short8*)(AsL + (r * 8 + ((1 * 4 + q + r) & 7)) * 16);
            #pragma unroll
            for (int n = 0; n < 2; ++n) {
                acc[m][n] = __builtin_amdgcn_mfma_f32_16x16x32_bf16(ah0, Bh[cur][n][0], acc[m][n], 0, 0, 0);
                acc[m][n] = __builtin_amdgcn_mfma_f32_16x16x32_bf16(al0, Bh[cur][n][0], acc[m][n], 0, 0, 0);
                acc[m][n] = __builtin_amdgcn_mfma_f32_16x16x32_bf16(ah0, Bl[cur][n][0], acc[m][n], 0, 0, 0);
                acc[m][n] = __builtin_amdgcn_mfma_f32_16x16x32_bf16(ah1, Bh[cur][n][1], acc[m][n], 0, 0, 0);
                acc[m][n] = __builtin_amdgcn_mfma_f32_16x16x32_bf16(al1, Bh[cur][n][1], acc[m][n], 0, 0, 0);
                acc[m][n] = __builtin_amdgcn_mfma_f32_16x16x32_bf16(ah1, Bl[cur][n][1], acc[m][n], 0, 0, 0);
            }
        }

        if (i < 7) {
            char* DH = smem + (sgrp * 2 + nxt) * 16384;
            ((int4*)DH)[lds0] = pa_h0;
            ((int4*)DH)[lds1] = pa_h1;
            ((int4*)(DH + 8192))[lds0] = pa_l0;
            ((int4*)(DH + 8192))[lds1] = pa_l1;
        }
        __syncthreads();
    }

    if (kh == 1) {
        #pragma unroll
        for (int m = 0; m < 4; ++m)
            #pragma unroll
            for (int n = 0; n < 2; ++n)
                #pragma unroll
                for (int r = 0; r < 4; ++r)
                    Gx[(g * 64 + m * 16 + q * 4 + r) * 36 + n * 16 + fr] = acc[m][n][r];
    }
    __syncthreads();
    if (kh == 0) {
        #pragma unroll
        for (int m = 0; m < 4; ++m)
            #pragma unroll
            for (int n = 0; n < 2; ++n)
                #pragma unroll
                for (int r = 0; r < 4; ++r) {
                    const int idx = (g * 64 + m * 16 + q * 4 + r) * 36 + n * 16 + fr;
                    Gx[idx] += acc[m][n][r];
                }
    }
    __syncthreads();

    const int rr = tid >> 3;
    const int c0 = (tid & 7) * 4;
    const int f = fbase + rr;
    const int gc = n0 + c0;
    const size_t gidx = (size_t)f * HH + gc;
    const float* ib = tokens ? (initE + (size_t)tokens[f * LL + t] * 4096)
                             : (initE + (size_t)f * 4096);
    const bool upd = lengths ? (t < lengths[f]) : true;

    float4 gv[4];
    #pragma unroll
    for (int gg = 0; gg < 4; ++gg) {
        gv[gg] = *(const float4*)&Gx[(gg * 64 + rr) * 36 + c0];
        const float4 ibv = *(const float4*)(ib + gg * 1024 + gc);
        gv[gg].x += ibv.x; gv[gg].y += ibv.y; gv[gg].z += ibv.z; gv[gg].w += ibv.w;
    }
    const float4 coldv = *(const float4*)(c_st + gidx);
    const float4 holdv = *(const float4*)(h_in + gidx);

    float4 cw, hw;
    unsigned short hb[4], lb[4];
    {
        const float* gi = (const float*)&gv[0];
        const float* gf = (const float*)&gv[1];
        const float* gn = (const float*)&gv[2];
        const float* go = (const float*)&gv[3];
        const float* co = (const float*)&coldv;
        const float* ho = (const float*)&holdv;
        #pragma unroll
        for (int j = 0; j < 4; ++j) {
            float cn = sigm(gf[j]) * co[j] + sigm(gi[j]) * tanh_fast(gn[j]);
            float hn = sigm(go[j]) * tanh_fast(cn);
            float cv = upd ? cn : co[j];
            float hv = upd ? hn : ho[j];
            ((float*)&cw)[j] = cv;
            ((float*)&hw)[j] = hv;
            split_bf16(hv, hb[j], lb[j]);
        }
    }
    *(float4*)(c_st + gidx) = cw;
    *(float4*)(h_out + gidx) = hw;
    uint2 hp, lp;
    hp.x = (unsigned)hb[0] | ((unsigned)hb[1] << 16);
    hp.y = (unsigned)hb[2] | ((unsigned)hb[3] << 16);
    lp.x = (unsigned)lb[0] | ((unsigned)lb[1] << 16);
    lp.y = (unsigned)lb[2] | ((unsigned)lb[3] << 16);
    *(uint2*)(hhi_o + gidx) = hp;
    *(uint2*)(hlo_o + gidx) = lp;
}

// ---------------------------------------------------------------------------
// Generic fp32 C[M][N] = A[M][K] @ W[N][K]^T + bias[N]
// grid (M/32, N/64), block 256; per thread 4x2.
// ---------------------------------------------------------------------------
__global__ __launch_bounds__(256) void gemm_bias(
    const float* __restrict__ A, const float* __restrict__ W,
    const float* __restrict__ bias, float* __restrict__ C,
    int N, int K)
{
    __shared__ __align__(16) float As[16][32];
    __shared__ __align__(16) float Bs[16][64];
    const int tid = threadIdx.x;
    const int tm = tid & 7;
    const int tn = tid >> 3;
    const int m0 = blockIdx.x * 32, n0 = blockIdx.y * 64;
    const int am = tid >> 3;
    const int ak = (tid & 7) * 2;
    const int br = tid >> 2;
    const int bk = (tid & 3) * 4;
    const float* arow = A + (size_t)(m0 + am) * K;
    const float* brow = W + (size_t)(n0 + br) * K;
    float acc[4][2] = {};
    const int tm4 = tm * 4, tn2 = tn * 2;

    for (int k0 = 0; k0 < K; k0 += 16) {
        __syncthreads();
        float2 av = *(const float2*)(arow + k0 + ak);
        float4 bv = *(const float4*)(brow + k0 + bk);
        As[ak][am] = av.x; As[ak + 1][am] = av.y;
        Bs[bk][br] = bv.x; Bs[bk + 1][br] = bv.y;
        Bs[bk + 2][br] = bv.z; Bs[bk + 3][br] = bv.w;
        __syncthreads();
        #pragma unroll
        for (int k = 0; k < 16; ++k) {
            float4 a = *(const float4*)&As[k][tm4];
            float2 b = *(const float2*)&Bs[k][tn2];
            acc[0][0] += a.x * b.x; acc[0][1] += a.x * b.y;
            acc[1][0] += a.y * b.x; acc[1][1] += a.y * b.y;
            acc[2][0] += a.z * b.x; acc[2][1] += a.z * b.y;
            acc[3][0] += a.w * b.x; acc[3][1] += a.w * b.y;
        }
    }
    float b0 = bias[n0 + tn2], b1 = bias[n0 + tn2 + 1];
    #pragma unroll
    for (int mi = 0; mi < 4; ++mi) {
        float2 o;
        o.x = acc[mi][0] + b0;
        o.y = acc[mi][1] + b1;
        *(float2*)(C + (size_t)(m0 + tm4 + mi) * N + n0 + tn2) = o;
    }
}

// ---------------------------------------------------------------------------
// pooled[b][n] = tanh(max_e (h[4b+e] @ W_mp^T) + b_mp)   (tanh monotone)
// ---------------------------------------------------------------------------
__global__ __launch_bounds__(256) void mp_pool(
    const float* __restrict__ h, const float* __restrict__ Wmp,
    const float* __restrict__ bmp, float* __restrict__ pooled)
{
    __shared__ __align__(16) float As[16][32];
    __shared__ __align__(16) float Bs[16][64];
    const int tid = threadIdx.x;
    const int tm = tid & 7;
    const int tn = tid >> 3;
    const int m0 = blockIdx.x * 32, n0 = blockIdx.y * 64;
    const int am = tid >> 3;
    const int ak = (tid & 7) * 2;
    const int br = tid >> 2;
    const int bk = (tid & 3) * 4;
    const float* arow = h + (size_t)(m0 + am) * HH;
    const float* brow = Wmp + (size_t)(n0 + br) * HH;
    float acc[4][2] = {};
    const int tm4 = tm * 4, tn2 = tn * 2;

    for (int k0 = 0; k0 < HH; k0 += 16) {
        __syncthreads();
        float2 av = *(const float2*)(arow + k0 + ak);
        float4 bv = *(const float4*)(brow + k0 + bk);
        As[ak][am] = av.x; As[ak + 1][am] = av.y;
        Bs[bk][br] = bv.x; Bs[bk + 1][br] = bv.y;
        Bs[bk + 2][br] = bv.z; Bs[bk + 3][br] = bv.w;
        __syncthreads();
        #pragma unroll
        for (int k = 0; k < 16; ++k) {
            float4 a = *(const float4*)&As[k][tm4];
            float2 b = *(const float2*)&Bs[k][tn2];
            acc[0][0] += a.x * b.x; acc[0][1] += a.x * b.y;
            acc[1][0] += a.y * b.x; acc[1][1] += a.y * b.y;
            acc[2][0] += a.z * b.x; acc[2][1] += a.z * b.y;
            acc[3][0] += a.w * b.x; acc[3][1] += a.w * b.y;
        }
    }
    float mx0 = fmaxf(fmaxf(acc[0][0], acc[1][0]), fmaxf(acc[2][0], acc[3][0]));
    float mx1 = fmaxf(fmaxf(acc[0][1], acc[1][1]), fmaxf(acc[2][1], acc[3][1]));
    mx0 += bmp[n0 + tn2];
    mx1 += bmp[n0 + tn2 + 1];
    float2 o;
    o.x = tanh_fast(mx0);
    o.y = tanh_fast(mx1);
    const int bidx = (m0 >> 2) + tm;
    *(float2*)(pooled + (size_t)bidx * HH + n0 + tn2) = o;
}

extern "C" void kernel_launch(void* const* d_in, const int* in_sizes, int n_in,
                              void* d_out, int out_size, void* d_ws, size_t ws_size,
                              hipStream_t stream)
{
    const int*   tokens_in   = (const int*)d_in[0];
    const int*   lengths_in  = (const int*)d_in[1];
    const int*   tokens_out  = (const int*)d_in[2];
    const int*   lengths_out = (const int*)d_in[3];
    const float* embedding   = (const float*)d_in[4];
    const float* W_ih_in     = (const float*)d_in[5];
    const float* W_hh_in     = (const float*)d_in[6];
    const float* b_in        = (const float*)d_in[7];
    const float* W_ih_out    = (const float*)d_in[8];
    const float* W_hh_out    = (const float*)d_in[9];
    const float* b_out       = (const float*)d_in[10];
    const float* W_ih_p      = (const float*)d_in[11];
    const float* W_hh_p      = (const float*)d_in[12];
    const float* b_p         = (const float*)d_in[13];
    const float* W_mp        = (const float*)d_in[14];
    const float* b_mp        = (const float*)d_in[15];
    const float* W_sm        = (const float*)d_in[16];
    const float* b_sm        = (const float*)d_in[17];
    float* out = (float*)d_out;

    // workspace layout (float units); total ~18.5M floats = 74 MB
    float* ws = (float*)d_ws;
    float* h_a      = ws;                  // 524288
    float* h_b      = ws + 524288;         // 524288
    float* c_st     = ws + 1048576;        // 524288
    float* embW_in  = ws + 1572864;        // 524288
    float* embW_out = ws + 2097152;        // 524288
    float* u_p      = ws + 2621440;        // 2097152
    float* pooled   = ws + 4718592;        // 131072
    ushort_t* hhi_a = (ushort_t*)(ws + 4849664);   // 524288 bf16
    ushort_t* hlo_a = (ushort_t*)(ws + 5111808);
    ushort_t* hhi_b = (ushort_t*)(ws + 5373952);
    ushort_t* hlo_b = (ushort_t*)(ws + 5636096);
    ushort_t* Whi_in  = (ushort_t*)(ws + 5898240); // 4194304 bf16 each
    ushort_t* Wlo_in  = (ushort_t*)(ws + 7995392);
    ushort_t* Whi_out = (ushort_t*)(ws + 10092544);
    ushort_t* Wlo_out = (ushort_t*)(ws + 12189696);
    ushort_t* Whi_p   = (ushort_t*)(ws + 14286848);
    ushort_t* Wlo_p   = (ushort_t*)(ws + 16384000);
    // barrier counter (R3/R4-verified single counter) at u_p[0]
    unsigned* barCnt  = (unsigned*)u_p;

    // zero h0's bf16 hi/lo (hhi_a/hlo_a adjacent) + all barrier state
    fillz<<<2048, 256, 0, stream>>>(ws + 4849664, 524288);
    fillz<<<8, 256, 0, stream>>>(u_p, 2048);

    // split the three recurrent weight matrices into bf16 hi/lo
    split_w<<<16384, 256, 0, stream>>>(W_hh_in,  Whi_in,  Wlo_in,  4194304);
    split_w<<<16384, 256, 0, stream>>>(W_hh_out, Whi_out, Wlo_out, 4194304);
    split_w<<<16384, 256, 0, stream>>>(W_hh_p,   Whi_p,   Wlo_p,   4194304);

    // embW = embedding @ W_ih^T + b  (x @ W_ih collapses to a gather)
    gemm_bias<<<dim3(4, 64), 256, 0, stream>>>(embedding, W_ih_in, b_in, embW_in, 4096, 128);
    gemm_bias<<<dim3(4, 64), 256, 0, stream>>>(embedding, W_ih_out, b_out, embW_out, 4096, 128);

    // --- persistent cooperative encoder: grid 256 (VERIFIED size), 1024 thr
    {
        void* kargs[] = {
            (void*)&hhi_a, (void*)&hlo_a, (void*)&hhi_b, (void*)&hlo_b,
            (void*)&h_a, (void*)&c_st,
            (void*)&Whi_in, (void*)&Wlo_in, (void*)&Whi_out, (void*)&Wlo_out,
            (void*)&embW_in, (void*)&embW_out,
            (void*)&tokens_in, (void*)&lengths_in,
            (void*)&tokens_out, (void*)&lengths_out,
            (void*)&barCnt
        };
        hipLaunchCooperativeKernel((void*)lstm_encoder_persistent,
                                   dim3(256), dim3(1024), kargs, 0, stream);
    }

    // decoder handoff: final h in h_a (fp32) + hhi_a/hlo_a (bf16), c in c_st
    float* hc = h_a;  ushort_t* hic = hhi_a;  ushort_t* loc = hlo_a;
    float* hn = h_b;  ushort_t* hin = hhi_b;  ushort_t* lon = hlo_b;

    // u_p = prev_h @ W_ih_p^T + b_p  (prev_h constant across all 16 steps)
    gemm_bias<<<dim3(16, 64), 256, 0, stream>>>(hc, W_ih_p, b_p, u_p, 4096, 1024);

    for (int t = 0; t < 16; ++t) {
        lstm_step_mfma<<<256, 512, 0, stream>>>(
            hc, hic, loc, hn, hin, lon, c_st, Whi_p, Wlo_p, u_p,
            nullptr, nullptr, t);
        mp_pool<<<dim3(16, 16), 256, 0, stream>>>(hn, W_mp, b_mp, pooled);
        gemm_bias<<<dim3(4, 16), 256, 0, stream>>>(pooled, W_sm, b_sm,
                                                   out + (size_t)t * (BB * PP), 1024, 1024);
        float* tf = hc; hc = hn; hn = tf;
        ushort_t* th = hic; hic = hin; hin = th;
        ushort_t* tl = loc; loc = lon; lon = tl;
    }
}

// Round 9
// 7754.746 us; speedup vs baseline: 1.5794x; 1.5794x over previous
//
#include <hip/hip_runtime.h>

#define FF 512
#define HH 1024
#define LL 128
#define BB 128
#define PP 1024

typedef short short8 __attribute__((ext_vector_type(8)));
typedef float floatx4 __attribute__((ext_vector_type(4)));
typedef unsigned short ushort_t;
typedef unsigned long long u64;

__device__ __forceinline__ float sigm(float x) {
    return 1.0f / (1.0f + __expf(-x));
}
// overflow-safe tanh: exp(-2|x|) underflows to 0 for large |x| -> +-1
__device__ __forceinline__ float tanh_fast(float x) {
    float ax = fabsf(x);
    float e = __expf(-2.0f * ax);
    float r = (1.0f - e) / (1.0f + e);
    return copysignf(r, x);
}

__device__ __forceinline__ unsigned short bf16_rtne(float x) {
    unsigned int u = __float_as_uint(x);
    return (unsigned short)((u + 0x7FFFu + ((u >> 16) & 1u)) >> 16);
}
__device__ __forceinline__ void split_bf16(float x, unsigned short& hi, unsigned short& lo) {
    hi = bf16_rtne(x);
    float hf = __uint_as_float(((unsigned int)hi) << 16);
    lo = bf16_rtne(x - hf);
}

// --- agent-scope h exchange: coherent across XCDs (verified R3/R4) ---
__device__ __forceinline__ int4 ld_h16(const ushort_t* p) {
    u64* q = (u64*)p;
    u64 a = __hip_atomic_load(q,     __ATOMIC_RELAXED, __HIP_MEMORY_SCOPE_AGENT);
    u64 b = __hip_atomic_load(q + 1, __ATOMIC_RELAXED, __HIP_MEMORY_SCOPE_AGENT);
    return make_int4((int)(unsigned)(a & 0xffffffffull), (int)(unsigned)(a >> 32),
                     (int)(unsigned)(b & 0xffffffffull), (int)(unsigned)(b >> 32));
}
__device__ __forceinline__ void st_h8(ushort_t* p, uint2 v) {
    u64 x = ((u64)v.y << 32) | (u64)v.x;
    __hip_atomic_store((u64*)p, x, __ATOMIC_RELAXED, __HIP_MEMORY_SCOPE_AGENT);
}
__device__ __forceinline__ float4 ld_f4_bypass(const float* p) {
    u64* q = (u64*)p;
    u64 a = __hip_atomic_load(q,     __ATOMIC_RELAXED, __HIP_MEMORY_SCOPE_AGENT);
    u64 b = __hip_atomic_load(q + 1, __ATOMIC_RELAXED, __HIP_MEMORY_SCOPE_AGENT);
    float4 r;
    ((u64*)&r)[0] = a;
    ((u64*)&r)[1] = b;
    return r;
}

// monotonic-counter grid barrier (VERIFIED R3/R4): tid0 arrives and spins;
// other waves park in the trailing __syncthreads. The leading __syncthreads
// drains every wave's vmcnt -> all h atomic-stores globally visible.
__device__ __forceinline__ void grid_barrier(unsigned* cnt, unsigned target, int tid) {
    __syncthreads();
    if (tid == 0) {
        __hip_atomic_fetch_add(cnt, 1u, __ATOMIC_RELAXED, __HIP_MEMORY_SCOPE_AGENT);
        while (__hip_atomic_load(cnt, __ATOMIC_RELAXED, __HIP_MEMORY_SCOPE_AGENT) < target) {
            __builtin_amdgcn_s_sleep(2);
        }
    }
    __syncthreads();
}

__global__ void fillz(float* p, int n) {
    int i = blockIdx.x * blockDim.x + threadIdx.x;
    if (i < n) p[i] = 0.0f;
}

// fp32 [n] -> bf16 (RTNE) [n]  — W is used hi-only now (2-term matmul)
__global__ void round_w(const float* __restrict__ W, ushort_t* __restrict__ hi, int n) {
    int i = blockIdx.x * blockDim.x + threadIdx.x;
    if (i < n) hi[i] = bf16_rtne(W[i]);
}

// ---------------------------------------------------------------------------
// Persistent cooperative encoder, v6 (2-TERM matmul):
// R7 falsified the latency theory (2x occupancy -> slower, BW down on same
// bytes): the step is bound by (a) the 3-term MFMA floor (~5.4us/step
// measured = theoretical) and (b) total coherent-path traffic (~80MB/step @
// ~2.5TB/s). This version drops the h_hi x W_lo term: W is bf16-rounded
// (h hi/lo split RETAINED). Effects: MFMA floor 5.2->3.5us; W stream
// halves (W_lo never read); per-XCD L2 set = W 1MB + h 2MB = 3MB < 4MB so
// W can stay L2-resident. Structure is otherwise byte-for-byte the VERIFIED
// R4 kernel: grid 256 x 512thr, wave=(gate g, K-half kh), acc[4][2],
// swizzled A LDS, B direct-to-reg dbuf, agent-atomic h, counter barrier.
// Accuracy: absmax expected ~2-4e-3 vs threshold 6.48e-3.
// ---------------------------------------------------------------------------
__global__ __launch_bounds__(512, 2) void lstm_encoder_persistent(
    ushort_t* __restrict__ hhiA, ushort_t* __restrict__ hloA,   // buf0 (zeroed)
    ushort_t* __restrict__ hhiB, ushort_t* __restrict__ hloB,   // buf1
    float* __restrict__ h_fin,   // fp32 final h   (h_a)
    float* __restrict__ c_fin,   // fp32 final c   (c_st)
    const ushort_t* __restrict__ Whi1,
    const ushort_t* __restrict__ Whi2,
    const float* __restrict__ emb1, const float* __restrict__ emb2,
    const int* __restrict__ tok1, const int* __restrict__ len1,
    const int* __restrict__ tok2, const int* __restrict__ len2,
    unsigned* __restrict__ barCnt)
{
    // A regions: (grp*2 + parity)*16384; within region hi @+0, lo @+8192.
    __shared__ __align__(16) char smem[65536];
    float* Gx = (float*)smem;            // epilogue reuse: [4][64][36] fp32

    const int tid = threadIdx.x;
    const int w = tid >> 6;              // wave 0..7
    const int g = w & 3;                 // gate
    const int kh = w >> 2;               // K-half 0/1
    const int l = tid & 63;
    const int q = l >> 4;                // k-quad 0..3
    const int fr = l & 15;               // fragment row/col

    // XCD-aware decode: xcd = id&7; by in {xcd, xcd+8, xcd+16, xcd+24}
    const int id = blockIdx.x;
    const int by = (id & 7) + 8 * ((id >> 3) & 3);
    const int bx = id >> 5;
    const int fbase = bx * 64;
    const int n0 = by * 32;

    // --- A staging map ---
    const int sgrp = tid >> 8;
    const int u = tid & 255;
    const int ar = u >> 2;
    const int s0 = u & 3;
    const size_t a_goff = (size_t)(fbase + ar) * HH + s0 * 8 + sgrp * 512;
    const int sw0 = (s0 + ar) & 7;
    const int sw1 = ((s0 + 4) + ar) & 7;
    const int lds0 = ar * 8 + sw0;
    const int lds1 = ar * 8 + sw1;

    // --- B fragment offsets (W-base-independent) ---
    const size_t brow0 = ((size_t)(g * HH) + n0 + fr) * HH + q * 8 + kh * 512;
    const size_t brow1 = ((size_t)(g * HH) + n0 + 16 + fr) * HH + q * 8 + kh * 512;

    // --- epilogue map + persistent cell state ---
    const int rr = tid >> 3;
    const int c0 = (tid & 7) * 4;
    const int f = fbase + rr;
    const int gc = n0 + c0;
    const size_t gidx = (size_t)f * HH + gc;
    float4 creg = make_float4(0.f, 0.f, 0.f, 0.f);
    float4 hreg = make_float4(0.f, 0.f, 0.f, 0.f);

    // B double buffer (hi only); prefetch chunk0 of t=0
    short8 Bh[2][2][2];
    #pragma unroll
    for (int kk = 0; kk < 2; ++kk) {
        Bh[0][0][kk] = *(const short8*)(Whi1 + brow0 + kk * 32);
        Bh[0][1][kk] = *(const short8*)(Whi1 + brow1 + kk * 32);
    }

    for (int t = 0; t < 256; ++t) {
        const int tt = t & 127;
        const bool ph2 = t >= 128;
        const ushort_t* Wh = ph2 ? Whi2 : Whi1;
        const ushort_t* WhN = (t >= 127) ? Whi2 : Whi1;  // base for t+1
        const float* emb = ph2 ? emb2 : emb1;
        const int* tok = ph2 ? tok2 : tok1;
        const int* len = ph2 ? len2 : len1;
        const ushort_t* rhh = (t & 1) ? hhiB : hhiA;
        const ushort_t* rhl = (t & 1) ? hloB : hloA;
        ushort_t* whh = (t & 1) ? hhiA : hhiB;
        ushort_t* whl = (t & 1) ? hloA : hloB;

        // A chunk 0 -> LDS region (sgrp, 0)   (agent-scope bypass loads)
        {
            int4 h0 = ld_h16(rhh + a_goff);
            int4 h1 = ld_h16(rhh + a_goff + 32);
            int4 l0v = ld_h16(rhl + a_goff);
            int4 l1v = ld_h16(rhl + a_goff + 32);
            char* R0 = smem + sgrp * 32768;
            ((int4*)R0)[lds0] = h0;
            ((int4*)R0)[lds1] = h1;
            ((int4*)(R0 + 8192))[lds0] = l0v;
            ((int4*)(R0 + 8192))[lds1] = l1v;
        }
        __syncthreads();

        floatx4 acc[4][2];
        #pragma unroll
        for (int m = 0; m < 4; ++m)
            #pragma unroll
            for (int n = 0; n < 2; ++n) acc[m][n] = (floatx4)(0.0f);

        int4 pa_h0, pa_h1, pa_l0, pa_l1;
        #pragma unroll 2
        for (int i = 0; i < 8; ++i) {
            const int cur = i & 1, nxt = cur ^ 1;
            const char* AsH = smem + (kh * 2 + cur) * 16384;
            const char* AsL = AsH + 8192;

            // A prefetch for local chunk i+1
            if (i < 7) {
                const int k0 = (i + 1) * 64;
                pa_h0 = ld_h16(rhh + a_goff + k0);
                pa_h1 = ld_h16(rhh + a_goff + k0 + 32);
                pa_l0 = ld_h16(rhl + a_goff + k0);
                pa_l1 = ld_h16(rhl + a_goff + k0 + 32);
            }
            // B prefetch: chunks 1..7 of this step, or chunk0 of NEXT step at i==7
            {
                const ushort_t* Bsh = (i < 7) ? Wh : WhN;
                const int k0 = (i < 7) ? (i + 1) * 64 : 0;
                #pragma unroll
                for (int kk = 0; kk < 2; ++kk) {
                    Bh[nxt][0][kk] = *(const short8*)(Bsh + brow0 + k0 + kk * 32);
                    Bh[nxt][1][kk] = *(const short8*)(Bsh + brow1 + k0 + kk * 32);
                }
            }

            // compute local chunk i from region (kh, cur): 2-term
            //   g += h_hi @ W + h_lo @ W      (W = bf16-rounded)
            #pragma unroll
            for (int m = 0; m < 4; ++m) {
                const int r = m * 16 + fr;
                short8 ah0 = *(const short8*)(AsH + (r * 8 + ((0 * 4 + q + r) & 7)) * 16);
                short8 ah1 = *(const short8*)(AsH + (r * 8 + ((1 * 4 + q + r) & 7)) * 16);
                short8 al0 = *(const short8*)(AsL + (r * 8 + ((0 * 4 + q + r) & 7)) * 16);
                short8 al1 = *(const short8*)(AsL + (r * 8 + ((1 * 4 + q + r) & 7)) * 16);
                #pragma unroll
                for (int n = 0; n < 2; ++n) {
                    acc[m][n] = __builtin_amdgcn_mfma_f32_16x16x32_bf16(ah0, Bh[cur][n][0], acc[m][n], 0, 0, 0);
                    acc[m][n] = __builtin_amdgcn_mfma_f32_16x16x32_bf16(al0, Bh[cur][n][0], acc[m][n], 0, 0, 0);
                    acc[m][n] = __builtin_amdgcn_mfma_f32_16x16x32_bf16(ah1, Bh[cur][n][1], acc[m][n], 0, 0, 0);
                    acc[m][n] = __builtin_amdgcn_mfma_f32_16x16x32_bf16(al1, Bh[cur][n][1], acc[m][n], 0, 0, 0);
                }
            }

            if (i < 7) {
                char* DH = smem + (sgrp * 2 + nxt) * 16384;
                ((int4*)DH)[lds0] = pa_h0;
                ((int4*)DH)[lds1] = pa_h1;
                ((int4*)(DH + 8192))[lds0] = pa_l0;
                ((int4*)(DH + 8192))[lds1] = pa_l1;
            }
            __syncthreads();
        }

        // --- K-half reduce (C/D layout: col=fr, row=q*4+reg) ---
        if (kh == 1) {
            #pragma unroll
            for (int m = 0; m < 4; ++m)
                #pragma unroll
                for (int n = 0; n < 2; ++n)
                    #pragma unroll
                    for (int r = 0; r < 4; ++r)
                        Gx[(g * 64 + m * 16 + q * 4 + r) * 36 + n * 16 + fr] = acc[m][n][r];
        }
        __syncthreads();
        if (kh == 0) {
            #pragma unroll
            for (int m = 0; m < 4; ++m)
                #pragma unroll
                for (int n = 0; n < 2; ++n)
                    #pragma unroll
                    for (int r = 0; r < 4; ++r) {
                        const int idx = (g * 64 + m * 16 + q * 4 + r) * 36 + n * 16 + fr;
                        Gx[idx] += acc[m][n][r];
                    }
        }
        __syncthreads();

        // --- fused cell update; c and mask-h in registers ---
        const float* ib = emb + (size_t)tok[f * LL + tt] * 4096;
        const bool upd = tt < len[f];

        float4 gv[4];
        #pragma unroll
        for (int gg = 0; gg < 4; ++gg) {
            gv[gg] = *(const float4*)&Gx[(gg * 64 + rr) * 36 + c0];
            const float4 ibv = ld_f4_bypass(ib + gg * 1024 + gc);
            gv[gg].x += ibv.x; gv[gg].y += ibv.y; gv[gg].z += ibv.z; gv[gg].w += ibv.w;
        }

        unsigned short hb[4], lb[4];
        {
            const float* gi = (const float*)&gv[0];
            const float* gf = (const float*)&gv[1];
            const float* gn = (const float*)&gv[2];
            const float* go = (const float*)&gv[3];
            float* cr = (float*)&creg;
            float* hr = (float*)&hreg;
            #pragma unroll
            for (int j = 0; j < 4; ++j) {
                float cn = sigm(gf[j]) * cr[j] + sigm(gi[j]) * tanh_fast(gn[j]);
                float hn = sigm(go[j]) * tanh_fast(cn);
                if (upd) { cr[j] = cn; hr[j] = hn; }
                split_bf16(hr[j], hb[j], lb[j]);
            }
        }
        uint2 hp, lp;
        hp.x = (unsigned)hb[0] | ((unsigned)hb[1] << 16);
        hp.y = (unsigned)hb[2] | ((unsigned)hb[3] << 16);
        lp.x = (unsigned)lb[0] | ((unsigned)lb[1] << 16);
        lp.y = (unsigned)lb[2] | ((unsigned)lb[3] << 16);
        st_h8(whh + gidx, hp);
        st_h8(whl + gidx, lp);
        if (t == 255) {
            *(float4*)(h_fin + gidx) = hreg;
            *(float4*)(c_fin + gidx) = creg;
        }
        grid_barrier(barCnt, 256u * (unsigned)(t + 1), tid);
    }
}

// ---------------------------------------------------------------------------
// bf16-split MFMA LSTM step (2-term) — used by the 16 decoder steps
// (initE = u_p, tokens/lengths = null).
// ---------------------------------------------------------------------------
__global__ __launch_bounds__(512, 2) void lstm_step_mfma(
    const float* __restrict__ h_in,
    const ushort_t* __restrict__ hhi,
    const ushort_t* __restrict__ hlo,
    float* __restrict__ h_out,
    ushort_t* __restrict__ hhi_o,
    ushort_t* __restrict__ hlo_o,
    float* __restrict__ c_st,
    const ushort_t* __restrict__ Whi,
    const float* __restrict__ initE,
    const int* __restrict__ tokens,
    const int* __restrict__ lengths,
    int t)
{
    __shared__ __align__(16) char smem[65536];
    float* Gx = (float*)smem;

    const int tid = threadIdx.x;
    const int w = tid >> 6;
    const int g = w & 3;
    const int kh = w >> 2;
    const int l = tid & 63;
    const int q = l >> 4;
    const int fr = l & 15;

    const int id = blockIdx.x;
    const int by = (id & 7) + 8 * ((id >> 3) & 3);
    const int bx = id >> 5;
    const int fbase = bx * 64;
    const int n0 = by * 32;

    const int sgrp = tid >> 8;
    const int u = tid & 255;
    const int ar = u >> 2;
    const int s0 = u & 3;
    const size_t a_goff = (size_t)(fbase + ar) * HH + s0 * 8 + sgrp * 512;
    const int sw0 = (s0 + ar) & 7;
    const int sw1 = ((s0 + 4) + ar) & 7;
    const int lds0 = ar * 8 + sw0;
    const int lds1 = ar * 8 + sw1;

    const size_t brow0 = ((size_t)(g * HH) + n0 + fr) * HH + q * 8 + kh * 512;
    const size_t brow1 = ((size_t)(g * HH) + n0 + 16 + fr) * HH + q * 8 + kh * 512;

    floatx4 acc[4][2];
    #pragma unroll
    for (int m = 0; m < 4; ++m)
        #pragma unroll
        for (int n = 0; n < 2; ++n) acc[m][n] = (floatx4)(0.0f);

    int4 pa_h0 = *(const int4*)(hhi + a_goff);
    int4 pa_h1 = *(const int4*)(hhi + a_goff + 32);
    int4 pa_l0 = *(const int4*)(hlo + a_goff);
    int4 pa_l1 = *(const int4*)(hlo + a_goff + 32);

    short8 Bh[2][2][2];
    #pragma unroll
    for (int kk = 0; kk < 2; ++kk) {
        Bh[0][0][kk] = *(const short8*)(Whi + brow0 + kk * 32);
        Bh[0][1][kk] = *(const short8*)(Whi + brow1 + kk * 32);
    }

    {
        char* R0 = smem + sgrp * 32768;
        ((int4*)R0)[lds0] = pa_h0;
        ((int4*)R0)[lds1] = pa_h1;
        ((int4*)(R0 + 8192))[lds0] = pa_l0;
        ((int4*)(R0 + 8192))[lds1] = pa_l1;
    }
    __syncthreads();

    #pragma unroll 2
    for (int i = 0; i < 8; ++i) {
        const int cur = i & 1, nxt = cur ^ 1;
        const char* AsH = smem + (kh * 2 + cur) * 16384;
        const char* AsL = AsH + 8192;

        if (i < 7) {
            const int k0 = (i + 1) * 64;
            pa_h0 = *(const int4*)(hhi + a_goff + k0);
            pa_h1 = *(const int4*)(hhi + a_goff + k0 + 32);
            pa_l0 = *(const int4*)(hlo + a_goff + k0);
            pa_l1 = *(const int4*)(hlo + a_goff + k0 + 32);
            #pragma unroll
            for (int kk = 0; kk < 2; ++kk) {
                Bh[nxt][0][kk] = *(const short8*)(Whi + brow0 + k0 + kk * 32);
                Bh[nxt][1][kk] = *(const short8*)(Whi + brow1 + k0 + kk * 32);
            }
        }

        #pragma unroll
        for (int m = 0; m < 4; ++m) {
            const int r = m * 16 + fr;
            short8 ah0 = *(const short8*)(AsH + (r * 8 + ((0 * 4 + q + r) & 7)) * 16);
            short8 ah1 = *(const short8*)(AsH + (r * 8 + ((1 * 4 + q + r) & 7)) * 16);
            short8 al0 = *(const short8*)(AsL + (r * 8 + ((0 * 4 + q + r) & 7)) * 16);
            short8 al1 = *(const short8*)(AsL + (r * 8 + ((1 * 4 + q + r) & 7)) * 16);
            #pragma unroll
            for (int n = 0; n < 2; ++n) {
                acc[m][n] = __builtin_amdgcn_mfma_f32_16x16x32_bf16(ah0, Bh[cur][n][0], acc[m][n], 0, 0, 0);
                acc[m][n] = __builtin_amdgcn_mfma_f32_16x16x32_bf16(al0, Bh[cur][n][0], acc[m][n], 0, 0, 0);
                acc[m][n] = __builtin_amdgcn_mfma_f32_16x16x32_bf16(ah1, Bh[cur][n][1], acc[m][n], 0, 0, 0);
                acc[m][n] = __builtin_amdgcn_mfma_f32_16x16x32_bf16(al1, Bh[cur][n][1], acc[m][n], 0, 0, 0);
            }
        }

        if (i < 7) {
            char* DH = smem + (sgrp * 2 + nxt) * 16384;
            ((int4*)DH)[lds0] = pa_h0;
            ((int4*)DH)[lds1] = pa_h1;
            ((int4*)(DH + 8192))[lds0] = pa_l0;
            ((int4*)(DH + 8192))[lds1] = pa_l1;
        }
        __syncthreads();
    }

    if (kh == 1) {
        #pragma unroll
        for (int m = 0; m < 4; ++m)
            #pragma unroll
            for (int n = 0; n < 2; ++n)
                #pragma unroll
                for (int r = 0; r < 4; ++r)
                    Gx[(g * 64 + m * 16 + q * 4 + r) * 36 + n * 16 + fr] = acc[m][n][r];
    }
    __syncthreads();
    if (kh == 0) {
        #pragma unroll
        for (int m = 0; m < 4; ++m)
            #pragma unroll
            for (int n = 0; n < 2; ++n)
                #pragma unroll
                for (int r = 0; r < 4; ++r) {
                    const int idx = (g * 64 + m * 16 + q * 4 + r) * 36 + n * 16 + fr;
                    Gx[idx] += acc[m][n][r];
                }
    }
    __syncthreads();

    const int rr = tid >> 3;
    const int c0 = (tid & 7) * 4;
    const int f = fbase + rr;
    const int gc = n0 + c0;
    const size_t gidx = (size_t)f * HH + gc;
    const float* ib = tokens ? (initE + (size_t)tokens[f * LL + t] * 4096)
                             : (initE + (size_t)f * 4096);
    const bool upd = lengths ? (t < lengths[f]) : true;

    float4 gv[4];
    #pragma unroll
    for (int gg = 0; gg < 4; ++gg) {
        gv[gg] = *(const float4*)&Gx[(gg * 64 + rr) * 36 + c0];
        const float4 ibv = *(const float4*)(ib + gg * 1024 + gc);
        gv[gg].x += ibv.x; gv[gg].y += ibv.y; gv[gg].z += ibv.z; gv[gg].w += ibv.w;
    }
    const float4 coldv = *(const float4*)(c_st + gidx);
    const float4 holdv = *(const float4*)(h_in + gidx);

    float4 cw, hw;
    unsigned short hb[4], lb[4];
    {
        const float* gi = (const float*)&gv[0];
        const float* gf = (const float*)&gv[1];
        const float* gn = (const float*)&gv[2];
        const float* go = (const float*)&gv[3];
        const float* co = (const float*)&coldv;
        const float* ho = (const float*)&holdv;
        #pragma unroll
        for (int j = 0; j < 4; ++j) {
            float cn = sigm(gf[j]) * co[j] + sigm(gi[j]) * tanh_fast(gn[j]);
            float hn = sigm(go[j]) * tanh_fast(cn);
            float cv = upd ? cn : co[j];
            float hv = upd ? hn : ho[j];
            ((float*)&cw)[j] = cv;
            ((float*)&hw)[j] = hv;
            split_bf16(hv, hb[j], lb[j]);
        }
    }
    *(float4*)(c_st + gidx) = cw;
    *(float4*)(h_out + gidx) = hw;
    uint2 hp, lp;
    hp.x = (unsigned)hb[0] | ((unsigned)hb[1] << 16);
    hp.y = (unsigned)hb[2] | ((unsigned)hb[3] << 16);
    lp.x = (unsigned)lb[0] | ((unsigned)lb[1] << 16);
    lp.y = (unsigned)lb[2] | ((unsigned)lb[3] << 16);
    *(uint2*)(hhi_o + gidx) = hp;
    *(uint2*)(hlo_o + gidx) = lp;
}

// ---------------------------------------------------------------------------
// Generic fp32 C[M][N] = A[M][K] @ W[N][K]^T + bias[N]
// grid (M/32, N/64), block 256; per thread 4x2.
// ---------------------------------------------------------------------------
__global__ __launch_bounds__(256) void gemm_bias(
    const float* __restrict__ A, const float* __restrict__ W,
    const float* __restrict__ bias, float* __restrict__ C,
    int N, int K)
{
    __shared__ __align__(16) float As[16][32];
    __shared__ __align__(16) float Bs[16][64];
    const int tid = threadIdx.x;
    const int tm = tid & 7;
    const int tn = tid >> 3;
    const int m0 = blockIdx.x * 32, n0 = blockIdx.y * 64;
    const int am = tid >> 3;
    const int ak = (tid & 7) * 2;
    const int br = tid >> 2;
    const int bk = (tid & 3) * 4;
    const float* arow = A + (size_t)(m0 + am) * K;
    const float* brow = W + (size_t)(n0 + br) * K;
    float acc[4][2] = {};
    const int tm4 = tm * 4, tn2 = tn * 2;

    for (int k0 = 0; k0 < K; k0 += 16) {
        __syncthreads();
        float2 av = *(const float2*)(arow + k0 + ak);
        float4 bv = *(const float4*)(brow + k0 + bk);
        As[ak][am] = av.x; As[ak + 1][am] = av.y;
        Bs[bk][br] = bv.x; Bs[bk + 1][br] = bv.y;
        Bs[bk + 2][br] = bv.z; Bs[bk + 3][br] = bv.w;
        __syncthreads();
        #pragma unroll
        for (int k = 0; k < 16; ++k) {
            float4 a = *(const float4*)&As[k][tm4];
            float2 b = *(const float2*)&Bs[k][tn2];
            acc[0][0] += a.x * b.x; acc[0][1] += a.x * b.y;
            acc[1][0] += a.y * b.x; acc[1][1] += a.y * b.y;
            acc[2][0] += a.z * b.x; acc[2][1] += a.z * b.y;
            acc[3][0] += a.w * b.x; acc[3][1] += a.w * b.y;
        }
    }
    float b0 = bias[n0 + tn2], b1 = bias[n0 + tn2 + 1];
    #pragma unroll
    for (int mi = 0; mi < 4; ++mi) {
        float2 o;
        o.x = acc[mi][0] + b0;
        o.y = acc[mi][1] + b1;
        *(float2*)(C + (size_t)(m0 + tm4 + mi) * N + n0 + tn2) = o;
    }
}

// ---------------------------------------------------------------------------
// pooled[b][n] = tanh(max_e (h[4b+e] @ W_mp^T) + b_mp)   (tanh monotone)
// ---------------------------------------------------------------------------
__global__ __launch_bounds__(256) void mp_pool(
    const float* __restrict__ h, const float* __restrict__ Wmp,
    const float* __restrict__ bmp, float* __restrict__ pooled)
{
    __shared__ __align__(16) float As[16][32];
    __shared__ __align__(16) float Bs[16][64];
    const int tid = threadIdx.x;
    const int tm = tid & 7;
    const int tn = tid >> 3;
    const int m0 = blockIdx.x * 32, n0 = blockIdx.y * 64;
    const int am = tid >> 3;
    const int ak = (tid & 7) * 2;
    const int br = tid >> 2;
    const int bk = (tid & 3) * 4;
    const float* arow = h + (size_t)(m0 + am) * HH;
    const float* brow = Wmp + (size_t)(n0 + br) * HH;
    float acc[4][2] = {};
    const int tm4 = tm * 4, tn2 = tn * 2;

    for (int k0 = 0; k0 < HH; k0 += 16) {
        __syncthreads();
        float2 av = *(const float2*)(arow + k0 + ak);
        float4 bv = *(const float4*)(brow + k0 + bk);
        As[ak][am] = av.x; As[ak + 1][am] = av.y;
        Bs[bk][br] = bv.x; Bs[bk + 1][br] = bv.y;
        Bs[bk + 2][br] = bv.z; Bs[bk + 3][br] = bv.w;
        __syncthreads();
        #pragma unroll
        for (int k = 0; k < 16; ++k) {
            float4 a = *(const float4*)&As[k][tm4];
            float2 b = *(const float2*)&Bs[k][tn2];
            acc[0][0] += a.x * b.x; acc[0][1] += a.x * b.y;
            acc[1][0] += a.y * b.x; acc[1][1] += a.y * b.y;
            acc[2][0] += a.z * b.x; acc[2][1] += a.z * b.y;
            acc[3][0] += a.w * b.x; acc[3][1] += a.w * b.y;
        }
    }
    float mx0 = fmaxf(fmaxf(acc[0][0], acc[1][0]), fmaxf(acc[2][0], acc[3][0]));
    float mx1 = fmaxf(fmaxf(acc[0][1], acc[1][1]), fmaxf(acc[2][1], acc[3][1]));
    mx0 += bmp[n0 + tn2];
    mx1 += bmp[n0 + tn2 + 1];
    float2 o;
    o.x = tanh_fast(mx0);
    o.y = tanh_fast(mx1);
    const int bidx = (m0 >> 2) + tm;
    *(float2*)(pooled + (size_t)bidx * HH + n0 + tn2) = o;
}

extern "C" void kernel_launch(void* const* d_in, const int* in_sizes, int n_in,
                              void* d_out, int out_size, void* d_ws, size_t ws_size,
                              hipStream_t stream)
{
    const int*   tokens_in   = (const int*)d_in[0];
    const int*   lengths_in  = (const int*)d_in[1];
    const int*   tokens_out  = (const int*)d_in[2];
    const int*   lengths_out = (const int*)d_in[3];
    const float* embedding   = (const float*)d_in[4];
    const float* W_ih_in     = (const float*)d_in[5];
    const float* W_hh_in     = (const float*)d_in[6];
    const float* b_in        = (const float*)d_in[7];
    const float* W_ih_out    = (const float*)d_in[8];
    const float* W_hh_out    = (const float*)d_in[9];
    const float* b_out       = (const float*)d_in[10];
    const float* W_ih_p      = (const float*)d_in[11];
    const float* W_hh_p      = (const float*)d_in[12];
    const float* b_p         = (const float*)d_in[13];
    const float* W_mp        = (const float*)d_in[14];
    const float* b_mp        = (const float*)d_in[15];
    const float* W_sm        = (const float*)d_in[16];
    const float* b_sm        = (const float*)d_in[17];
    float* out = (float*)d_out;

    // workspace layout (float units); total ~18.5M floats = 74 MB
    float* ws = (float*)d_ws;
    float* h_a      = ws;                  // 524288
    float* h_b      = ws + 524288;         // 524288
    float* c_st     = ws + 1048576;        // 524288
    float* embW_in  = ws + 1572864;        // 524288
    float* embW_out = ws + 2097152;        // 524288
    float* u_p      = ws + 2621440;        // 2097152
    float* pooled   = ws + 4718592;        // 131072
    ushort_t* hhi_a = (ushort_t*)(ws + 4849664);   // 524288 bf16
    ushort_t* hlo_a = (ushort_t*)(ws + 5111808);
    ushort_t* hhi_b = (ushort_t*)(ws + 5373952);
    ushort_t* hlo_b = (ushort_t*)(ws + 5636096);
    ushort_t* Whi_in  = (ushort_t*)(ws + 5898240); // 4194304 bf16 each
    ushort_t* Whi_out = (ushort_t*)(ws + 10092544);
    ushort_t* Whi_p   = (ushort_t*)(ws + 14286848);
    // barrier counter (R3/R4-verified single counter) at u_p[0]
    unsigned* barCnt  = (unsigned*)u_p;

    // zero h0's bf16 hi/lo (hhi_a/hlo_a adjacent) + all barrier state
    fillz<<<2048, 256, 0, stream>>>(ws + 4849664, 524288);
    fillz<<<8, 256, 0, stream>>>(u_p, 2048);

    // round the three recurrent weight matrices to bf16 (hi only; 2-term)
    round_w<<<16384, 256, 0, stream>>>(W_hh_in,  Whi_in,  4194304);
    round_w<<<16384, 256, 0, stream>>>(W_hh_out, Whi_out, 4194304);
    round_w<<<16384, 256, 0, stream>>>(W_hh_p,   Whi_p,   4194304);

    // embW = embedding @ W_ih^T + b  (x @ W_ih collapses to a gather)
    gemm_bias<<<dim3(4, 64), 256, 0, stream>>>(embedding, W_ih_in, b_in, embW_in, 4096, 128);
    gemm_bias<<<dim3(4, 64), 256, 0, stream>>>(embedding, W_ih_out, b_out, embW_out, 4096, 128);

    // --- persistent cooperative encoder: both 128-step phases, one launch ---
    {
        void* kargs[] = {
            (void*)&hhi_a, (void*)&hlo_a, (void*)&hhi_b, (void*)&hlo_b,
            (void*)&h_a, (void*)&c_st,
            (void*)&Whi_in, (void*)&Whi_out,
            (void*)&embW_in, (void*)&embW_out,
            (void*)&tokens_in, (void*)&lengths_in,
            (void*)&tokens_out, (void*)&lengths_out,
            (void*)&barCnt
        };
        hipLaunchCooperativeKernel((void*)lstm_encoder_persistent,
                                   dim3(256), dim3(512), kargs, 0, stream);
    }

    // decoder handoff: final h in h_a (fp32) + hhi_a/hlo_a (bf16), c in c_st
    float* hc = h_a;  ushort_t* hic = hhi_a;  ushort_t* loc = hlo_a;
    float* hn = h_b;  ushort_t* hin = hhi_b;  ushort_t* lon = hlo_b;

    // u_p = prev_h @ W_ih_p^T + b_p  (prev_h constant across all 16 steps)
    gemm_bias<<<dim3(16, 64), 256, 0, stream>>>(hc, W_ih_p, b_p, u_p, 4096, 1024);

    for (int t = 0; t < 16; ++t) {
        lstm_step_mfma<<<256, 512, 0, stream>>>(
            hc, hic, loc, hn, hin, lon, c_st, Whi_p, u_p,
            nullptr, nullptr, t);
        mp_pool<<<dim3(16, 16), 256, 0, stream>>>(hn, W_mp, b_mp, pooled);
        gemm_bias<<<dim3(4, 16), 256, 0, stream>>>(pooled, W_sm, b_sm,
                                                   out + (size_t)t * (BB * PP), 1024, 1024);
        float* tf = hc; hc = hn; hn = tf;
        ushort_t* th = hic; hic = hin; hin = th;
        ushort_t* tl = loc; loc = lon; lon = tl;
    }
}